// Round 6
// baseline (5036.616 us; speedup 1.0000x reference)
//
#include <hip/hip_runtime.h>
#include <stdint.h>

typedef unsigned int u32;
typedef unsigned long long u64;
typedef unsigned short u16;

#define NB 8
#define NN 8192
#define NP 1024
#define NS 32
#define MROWS (NB * NP * NS) /* 262144 */

__device__ __forceinline__ u16 f2bf(float f) {
  u32 u = __float_as_uint(f);
  u32 r = u + 0x7FFFu + ((u >> 16) & 1u);   // round-to-nearest-even
  return (u16)(r >> 16);
}
__device__ __forceinline__ float bf2f(u32 h) { return __uint_as_float(h << 16); }
__device__ __forceinline__ float ldv(const float* p, size_t i) { return p[i]; }
__device__ __forceinline__ float ldv(const u16* p, size_t i) { return bf2f(p[i]); }

// ---------------- zero BN stats accumulators (512 doubles) ----------------
__global__ void zero_stats(double* __restrict__ stats) {
  int g = blockIdx.x * 256 + threadIdx.x;
  if (g < 512) stats[g] = 0.0;
}

// ---------------- FPS: one block (1024 thr) per batch [verified via out0] ----------------
__global__ __launch_bounds__(1024) void fps_kernel(const float* __restrict__ xyz,
                                                   float* __restrict__ out0,      // [B][3][P]
                                                   float* __restrict__ newxyzT) { // [B][P][3]
  const int b = blockIdx.x;
  const int t = threadIdx.x;
  const float* xb = xyz + (size_t)b * 3 * NN;
  float px[8], py[8], pz[8], dist[8];
#pragma unroll
  for (int j = 0; j < 8; ++j) {
    int n = t + j * 1024;
    px[j] = xb[n];
    py[j] = xb[NN + n];
    pz[j] = xb[2 * NN + n];
    dist[j] = 1e10f;
  }
  __shared__ u64 redk[16];
  __shared__ float redx[16], redy[16], redz[16];
  __shared__ float wxs, wys, wzs;
  if (t == 0) { wxs = px[0]; wys = py[0]; wzs = pz[0]; }
  __syncthreads();
  const int lane = t & 63, wid = t >> 6;
  for (int s = 0; s < NP; ++s) {
    float cx = wxs, cy = wys, cz = wzs;
    if (t == 0) {
      out0[b * 3 * NP + s] = cx;
      out0[b * 3 * NP + NP + s] = cy;
      out0[b * 3 * NP + 2 * NP + s] = cz;
      float* q = newxyzT + ((size_t)b * NP + s) * 3;
      q[0] = cx; q[1] = cy; q[2] = cz;
    }
    u64 bk = 0; float bx = 0.f, by = 0.f, bz = 0.f;
#pragma unroll
    for (int j = 0; j < 8; ++j) {
      float dx = __fsub_rn(px[j], cx), dy = __fsub_rn(py[j], cy), dz = __fsub_rn(pz[j], cz);
      float d = __fadd_rn(__fadd_rn(__fmul_rn(dx, dx), __fmul_rn(dy, dy)), __fmul_rn(dz, dz));
      float dj = fminf(dist[j], d);
      dist[j] = dj;
      u64 key = ((u64)__float_as_uint(dj) << 13) | (u32)(8191 - (t + j * 1024));
      if (key > bk) { bk = key; bx = px[j]; by = py[j]; bz = pz[j]; }
    }
#pragma unroll
    for (int m = 32; m > 0; m >>= 1) {
      u64 ok = __shfl_xor(bk, m);
      float ox = __shfl_xor(bx, m), oy = __shfl_xor(by, m), oz = __shfl_xor(bz, m);
      if (ok > bk) { bk = ok; bx = ox; by = oy; bz = oz; }
    }
    if (lane == 0) { redk[wid] = bk; redx[wid] = bx; redy[wid] = by; redz[wid] = bz; }
    __syncthreads();
    if (wid == 0) {
      u64 k2 = (lane < 16) ? redk[lane] : 0ull;
      float x2 = (lane < 16) ? redx[lane] : 0.f;
      float y2 = (lane < 16) ? redy[lane] : 0.f;
      float z2 = (lane < 16) ? redz[lane] : 0.f;
#pragma unroll
      for (int m = 8; m > 0; m >>= 1) {
        u64 ok = __shfl_xor(k2, m);
        float ox = __shfl_xor(x2, m), oy = __shfl_xor(y2, m), oz = __shfl_xor(z2, m);
        if (ok > k2) { k2 = ok; x2 = ox; y2 = oy; z2 = oz; }
      }
      if (lane == 0) { wxs = x2; wys = y2; wzs = z2; }
    }
    __syncthreads();
  }
}

// ---------------- kNN: expansion formula with FMA k-chain dot (BLAS/XLA semantics) ----------------
// d2 = (A - 2*dot) + sq,  dot = fma(qz,z, fma(qy,y, qx*x)),  A/sq = rn square-chains.
// Can be slightly negative -> sign-flip transform for monotone u32 ordering.
// Ties -> lower index (stable argsort), via min over (sb<<32 | n).
__global__ __launch_bounds__(64) void knn_expansion_fma(const float* __restrict__ xyz,
                                                        const float* __restrict__ newxyzT,
                                                        int* __restrict__ knn) {
  const int q = blockIdx.x;       // b*1024 + p
  const int b = q >> 10;
  const int lane = threadIdx.x;
  __shared__ float sd[NN];        // 32 KB (sign-flipped sortable keys as float-bits)
  const float* qp = newxyzT + (size_t)q * 3;
  const float qx = qp[0], qy = qp[1], qz = qp[2];
  const float A = __fadd_rn(__fadd_rn(__fmul_rn(qx, qx), __fmul_rn(qy, qy)), __fmul_rn(qz, qz));
  const float* xb = xyz + (size_t)b * 3 * NN;
  for (int n = lane; n < NN; n += 64) {
    float x = xb[n], y = xb[NN + n], z = xb[2 * NN + n];
    float dot = fmaf(qz, z, fmaf(qy, y, __fmul_rn(qx, x)));
    float sq = __fadd_rn(__fadd_rn(__fmul_rn(x, x), __fmul_rn(y, y)), __fmul_rn(z, z));
    float d2 = __fadd_rn(__fsub_rn(A, __fmul_rn(2.0f, dot)), sq);
    u32 u = __float_as_uint(d2);
    u32 sb = u ^ (u32)((((int)u) >> 31) | 0x80000000u);  // monotone map (handles negatives)
    sd[n] = __uint_as_float(sb);
  }
  __syncthreads();
  for (int it = 0; it < NS; ++it) {
    u64 bk = ~0ull;
    for (int n = lane; n < NN; n += 64) {
      u64 key = ((u64)__float_as_uint(sd[n]) << 32) | (u32)n;
      if (key < bk) bk = key;
    }
#pragma unroll
    for (int m = 32; m > 0; m >>= 1) {
      u64 ok = __shfl_xor(bk, m);
      if (ok < bk) bk = ok;
    }
    int bi = (int)(bk & 0xFFFFFFFFull);
    if (lane == 0) knn[(size_t)q * NS + it] = bi;
    if ((bi & 63) == lane) sd[bi] = __uint_as_float(0xFFFFFFFFu);  // max key = invalidated
    __syncthreads();
  }
}

// ---------------- conv1 (naive): one thread per row; feat=[rel3, pts64] @ w1^T + b1 ----------------
__global__ __launch_bounds__(256) void conv1_naive(const float* __restrict__ xyz,
                                                   const float* __restrict__ newxyzT,
                                                   const float* __restrict__ points,
                                                   const int* __restrict__ knn,
                                                   const float* __restrict__ w1,
                                                   const float* __restrict__ b1,
                                                   float* __restrict__ z1) {
  __shared__ float wl[64 * 67];
  __shared__ float bl[64];
  for (int i = threadIdx.x; i < 64 * 67; i += 256) wl[i] = w1[i];
  if (threadIdx.x < 64) bl[threadIdx.x] = b1[threadIdx.x];
  __syncthreads();
  int r = blockIdx.x * 256 + threadIdx.x;       // global row (q,s), 0..262143
  int b = r >> 15;
  int q = r >> 5;
  int idx = knn[r];
  float feat[67];
#pragma unroll
  for (int e = 0; e < 3; ++e)
    feat[e] = xyz[((size_t)b * 3 + e) * NN + idx] - newxyzT[(size_t)q * 3 + e];
#pragma unroll
  for (int c = 0; c < 64; ++c)
    feat[3 + c] = points[((size_t)b * 64 + c) * NN + idx];
  for (int o = 0; o < 64; ++o) {
    float acc = bl[o];
    const float* wr = &wl[o * 67];
#pragma unroll
    for (int c = 0; c < 67; ++c) acc = fmaf(feat[c], wr[c], acc);
    z1[(size_t)r * 64 + o] = acc;
  }
}

// ---------------- per-channel sum/sumsq, f64 accumulation + f64 atomics ----------------
template <int C, typename T>
__global__ __launch_bounds__(256) void stats_kernel(const T* __restrict__ z,
                                                    double* __restrict__ sums, int M) {
  const int RPB = 256 / C;
  int c = threadIdx.x % C;
  int rg = threadIdx.x / C;
  int row = blockIdx.x * RPB + rg;
  int stride = gridDim.x * RPB;
  double s = 0.0, s2 = 0.0;
  for (; row < M; row += stride) {
    double v = (double)ldv(z, (size_t)row * C + c);
    s += v;
    s2 = fma(v, v, s2);
  }
  __shared__ double ls[2][256];
  ls[0][threadIdx.x] = s;
  ls[1][threadIdx.x] = s2;
  __syncthreads();
  if (threadIdx.x < C) {
    for (int k = 1; k < RPB; ++k) {
      s += ls[0][threadIdx.x + k * C];
      s2 += ls[1][threadIdx.x + k * C];
    }
    atomicAdd(&sums[c], s);
    atomicAdd(&sums[C + c], s2);
  }
}

// aff helper: a = g/sqrt(var+eps), cadd = bt - mean*a   (f64 stats -> f32)
__device__ __forceinline__ void bn_aff(const double* st, int C, int c,
                                       const float* g, const float* bt,
                                       float& a, float& cadd) {
  double mean = st[c] / (double)MROWS;
  double var = st[C + c] / (double)MROWS - mean * mean;
  if (var < 0.0) var = 0.0;
  double ad = (double)g[c] / sqrt(var + 1e-5);
  a = (float)ad;
  cadd = (float)((double)bt[c] - mean * ad);
}

// ---------------- conv2 (naive): bn1+relu on z1(f32) @ w2^T + b2 -> z2 bf16 ----------------
__global__ __launch_bounds__(256) void conv2_naive(const float* __restrict__ z1,
                                                   const double* __restrict__ stats1,
                                                   const float* __restrict__ g1,
                                                   const float* __restrict__ bt1,
                                                   const float* __restrict__ w2,
                                                   const float* __restrict__ b2,
                                                   u16* __restrict__ z2) {
  __shared__ float wl[64 * 64];
  __shared__ float sa[64], sc[64], bl[64];
  for (int i = threadIdx.x; i < 64 * 64; i += 256) wl[i] = w2[i];
  if (threadIdx.x < 64) {
    bn_aff(stats1, 64, threadIdx.x, g1, bt1, sa[threadIdx.x], sc[threadIdx.x]);
    bl[threadIdx.x] = b2[threadIdx.x];
  }
  __syncthreads();
  int r = blockIdx.x * 256 + threadIdx.x;
  float x[64];
#pragma unroll
  for (int c = 0; c < 64; ++c)
    x[c] = fmaxf(0.f, fmaf(sa[c], z1[(size_t)r * 64 + c], sc[c]));
  for (int o = 0; o < 64; ++o) {
    float acc = bl[o];
    const float* wr = &wl[o * 64];
#pragma unroll
    for (int c = 0; c < 64; ++c) acc = fmaf(x[c], wr[c], acc);
    z2[(size_t)r * 64 + o] = f2bf(acc);
  }
}

// ---------------- conv3 (naive): bn2+relu on z2(bf16) @ w3^T + b3 -> z3 bf16 ----------------
__global__ __launch_bounds__(256) void conv3_naive(const u16* __restrict__ z2,
                                                   const double* __restrict__ stats2,
                                                   const float* __restrict__ g2,
                                                   const float* __restrict__ bt2,
                                                   const float* __restrict__ w3,
                                                   const float* __restrict__ b3,
                                                   u16* __restrict__ z3) {
  __shared__ float wl[128 * 64];
  __shared__ float sa[64], sc[64], bl[128];
  for (int i = threadIdx.x; i < 128 * 64; i += 256) wl[i] = w3[i];
  if (threadIdx.x < 64)
    bn_aff(stats2, 64, threadIdx.x, g2, bt2, sa[threadIdx.x], sc[threadIdx.x]);
  if (threadIdx.x < 128) bl[threadIdx.x] = b3[threadIdx.x];
  __syncthreads();
  int r = blockIdx.x * 256 + threadIdx.x;
  float x[64];
#pragma unroll
  for (int c = 0; c < 64; ++c)
    x[c] = fmaxf(0.f, fmaf(sa[c], bf2f(z2[(size_t)r * 64 + c]), sc[c]));
  for (int o = 0; o < 128; ++o) {
    float acc = bl[o];
    const float* wr = &wl[o * 64];
#pragma unroll
    for (int c = 0; c < 64; ++c) acc = fmaf(x[c], wr[c], acc);
    z3[(size_t)r * 128 + o] = f2bf(acc);
  }
}

// ---------------- bn3 + max over S (naive): one thread per (o, q) ----------------
__global__ __launch_bounds__(256) void bnmax_naive(const u16* __restrict__ z3,
                                                   const double* __restrict__ stats3,
                                                   const float* __restrict__ g3,
                                                   const float* __restrict__ bt3,
                                                   float* __restrict__ out1) {
  int tid = blockIdx.x * 256 + threadIdx.x;   // 0 .. 128*8192-1
  int o = tid >> 13;                          // 0..127
  int q = tid & 8191;                         // 0..8191
  int b = q >> 10, p = q & 1023;
  float a, cadd;
  bn_aff(stats3, 128, o, g3, bt3, a, cadd);
  float m = -3.4e38f;
  size_t base = (size_t)q * NS * 128 + o;
#pragma unroll
  for (int s = 0; s < NS; ++s) {
    float v = bf2f(z3[base + (size_t)s * 128]);
    m = fmaxf(m, fmaf(a, v, cadd));
  }
  out1[((size_t)b * 128 + o) * NP + p] = m;
}

// ---------------- host launch ----------------
extern "C" void kernel_launch(void* const* d_in, const int* in_sizes, int n_in,
                              void* d_out, int out_size, void* d_ws, size_t ws_size,
                              hipStream_t stream) {
  const float* xyz = (const float*)d_in[0];
  const float* points = (const float*)d_in[1];
  const float* w1 = (const float*)d_in[2];
  const float* b1 = (const float*)d_in[3];
  const float* g1 = (const float*)d_in[4];
  const float* bt1 = (const float*)d_in[5];
  const float* w2 = (const float*)d_in[6];
  const float* b2 = (const float*)d_in[7];
  const float* g2 = (const float*)d_in[8];
  const float* bt2 = (const float*)d_in[9];
  const float* w3 = (const float*)d_in[10];
  const float* b3 = (const float*)d_in[11];
  const float* g3 = (const float*)d_in[12];
  const float* bt3 = (const float*)d_in[13];
  float* out0 = (float*)d_out;             // [8][3][1024]
  float* out1 = out0 + NB * 3 * NP;        // [8][128][1024]

  // Compact workspace, tail-first (total 98 MB):
  //   [0, 96K)        newxyzT f32 [8][1024][3]
  //   [128K, 1.125M)  knn i32 [8][1024][32]
  //   [1.5M, 1.504M)  stats f64 [512]  (L1: 0..127, L2: 128..255, L3: 256..511)
  //   [2M, 66M)       z1 f32 [262144][64]   -> dead after conv2 -> z3 bf16 overlays
  //   [66M, 98M)      z2 bf16 [262144][64]
  char* ws = (char*)d_ws;
  float* newxyzT = (float*)ws;
  int* knn = (int*)(ws + 128 * 1024);
  double* stats = (double*)(ws + 1536 * 1024);
  float* z1 = (float*)(ws + (size_t)2 * 1024 * 1024);
  u16* z3 = (u16*)z1;                                       // alias: z1 dead before conv3
  u16* z2 = (u16*)(ws + (size_t)66 * 1024 * 1024);

  zero_stats<<<2, 256, 0, stream>>>(stats);
  fps_kernel<<<8, 1024, 0, stream>>>(xyz, out0, newxyzT);
  knn_expansion_fma<<<NB * NP, 64, 0, stream>>>(xyz, newxyzT, knn);
  conv1_naive<<<1024, 256, 0, stream>>>(xyz, newxyzT, points, knn, w1, b1, z1);
  stats_kernel<64, float><<<512, 256, 0, stream>>>(z1, stats + 0, MROWS);
  conv2_naive<<<1024, 256, 0, stream>>>(z1, stats + 0, g1, bt1, w2, b2, z2);
  stats_kernel<64, u16><<<512, 256, 0, stream>>>(z2, stats + 128, MROWS);
  conv3_naive<<<1024, 256, 0, stream>>>(z2, stats + 128, g2, bt2, w3, b3, z3);
  stats_kernel<128, u16><<<512, 256, 0, stream>>>(z3, stats + 256, MROWS);
  bnmax_naive<<<4096, 256, 0, stream>>>(z3, stats + 256, g3, bt3, out1);
}

// Round 7
// 4066.263 us; speedup vs baseline: 1.2386x; 1.2386x over previous
//
#include <hip/hip_runtime.h>
#include <stdint.h>

typedef unsigned int u32;
typedef unsigned long long u64;
typedef unsigned short u16;

#define NB 8
#define NN 8192
#define NP 1024
#define NS 32
#define MROWS (NB * NP * NS) /* 262144 */

__device__ __forceinline__ u16 f2bf(float f) {
  u32 u = __float_as_uint(f);
  u32 r = u + 0x7FFFu + ((u >> 16) & 1u);   // round-to-nearest-even
  return (u16)(r >> 16);
}
__device__ __forceinline__ float bf2f(u32 h) { return __uint_as_float(h << 16); }
__device__ __forceinline__ u32 pk2(float lo, float hi) {
  return (u32)f2bf(lo) | ((u32)f2bf(hi) << 16);
}
__device__ __forceinline__ float ldv(const float* p, size_t i) { return p[i]; }
__device__ __forceinline__ float ldv(const u16* p, size_t i) { return bf2f(p[i]); }

// ---------------- zero BN stats accumulators (512 doubles) ----------------
__global__ void zero_stats(double* __restrict__ stats) {
  int g = blockIdx.x * 256 + threadIdx.x;
  if (g < 512) stats[g] = 0.0;
}

// ---------------- FPS: 256 thr/block, 1 barrier/step, key-only reduce ----------------
// Arithmetic and selection bit-identical to the verified 1024-thr version:
// d = ((dx*dx)+(dy*dy))+(dz*dz) rn chain; dist=min; argmax with first-index
// tie-break via packed key (dbits<<13 | 8191-idx), u64 max.
__global__ __launch_bounds__(256) void fps_kernel(const float* __restrict__ xyz,
                                                  float* __restrict__ out0,      // [B][3][P]
                                                  float* __restrict__ newxyzT) { // [B][P][3]
  const int b = blockIdx.x;
  const int t = threadIdx.x;   // 0..255
  const float* xb = xyz + (size_t)b * 3 * NN;
  float px[32], py[32], pz[32], dist[32];
#pragma unroll
  for (int j = 0; j < 32; ++j) {
    int n = t + j * 256;
    px[j] = xb[n];
    py[j] = xb[NN + n];
    pz[j] = xb[2 * NN + n];
    dist[j] = 1e10f;
  }
  __shared__ u64 red[2][4];
  const int lane = t & 63, wid = t >> 6;
  float cx = xb[0], cy = xb[NN], cz = xb[2 * NN];   // farthest = 0 initially
  for (int s = 0; s < NP; ++s) {
    if (t == 0) {   // emit centroid BEFORE update (cents[s] = farthest before step)
      out0[b * 3 * NP + s] = cx;
      out0[b * 3 * NP + NP + s] = cy;
      out0[b * 3 * NP + 2 * NP + s] = cz;
      float* qq = newxyzT + ((size_t)b * NP + s) * 3;
      qq[0] = cx; qq[1] = cy; qq[2] = cz;
    }
    u64 bk = 0;
#pragma unroll
    for (int j = 0; j < 32; ++j) {
      float dx = __fsub_rn(px[j], cx), dy = __fsub_rn(py[j], cy), dz = __fsub_rn(pz[j], cz);
      float d = __fadd_rn(__fadd_rn(__fmul_rn(dx, dx), __fmul_rn(dy, dy)), __fmul_rn(dz, dz));
      float dj = fminf(dist[j], d);
      dist[j] = dj;
      u64 key = ((u64)__float_as_uint(dj) << 13) | (u32)(8191 - (t + j * 256));
      bk = key > bk ? key : bk;
    }
#pragma unroll
    for (int m = 32; m > 0; m >>= 1) {
      u64 ok = __shfl_xor(bk, m);
      bk = ok > bk ? ok : bk;
    }
    if (lane == 0) red[s & 1][wid] = bk;
    __syncthreads();   // single barrier: parity buffer protects cross-iter reuse
    u64 r0 = red[s & 1][0], r1 = red[s & 1][1];
    u64 r2 = red[s & 1][2], r3 = red[s & 1][3];
    u64 m01 = r0 > r1 ? r0 : r1;
    u64 m23 = r2 > r3 ? r2 : r3;
    bk = m01 > m23 ? m01 : m23;
    int widx = 8191 - (int)(bk & 8191ull);
    cx = xb[widx]; cy = xb[NN + widx]; cz = xb[2 * NN + widx];  // wave-uniform loads
  }
}

// ---------------- kNN: expansion formula with FMA k-chain dot [FROZEN — verified] ----------------
__global__ __launch_bounds__(64) void knn_expansion_fma(const float* __restrict__ xyz,
                                                        const float* __restrict__ newxyzT,
                                                        int* __restrict__ knn) {
  const int q = blockIdx.x;       // b*1024 + p
  const int b = q >> 10;
  const int lane = threadIdx.x;
  __shared__ float sd[NN];        // 32 KB (sign-flipped sortable keys as float-bits)
  const float* qp = newxyzT + (size_t)q * 3;
  const float qx = qp[0], qy = qp[1], qz = qp[2];
  const float A = __fadd_rn(__fadd_rn(__fmul_rn(qx, qx), __fmul_rn(qy, qy)), __fmul_rn(qz, qz));
  const float* xb = xyz + (size_t)b * 3 * NN;
  for (int n = lane; n < NN; n += 64) {
    float x = xb[n], y = xb[NN + n], z = xb[2 * NN + n];
    float dot = fmaf(qz, z, fmaf(qy, y, __fmul_rn(qx, x)));
    float sq = __fadd_rn(__fadd_rn(__fmul_rn(x, x), __fmul_rn(y, y)), __fmul_rn(z, z));
    float d2 = __fadd_rn(__fsub_rn(A, __fmul_rn(2.0f, dot)), sq);
    u32 u = __float_as_uint(d2);
    u32 sb = u ^ (u32)((((int)u) >> 31) | 0x80000000u);  // monotone map (handles negatives)
    sd[n] = __uint_as_float(sb);
  }
  __syncthreads();
  for (int it = 0; it < NS; ++it) {
    u64 bk = ~0ull;
    for (int n = lane; n < NN; n += 64) {
      u64 key = ((u64)__float_as_uint(sd[n]) << 32) | (u32)n;
      if (key < bk) bk = key;
    }
#pragma unroll
    for (int m = 32; m > 0; m >>= 1) {
      u64 ok = __shfl_xor(bk, m);
      if (ok < bk) bk = ok;
    }
    int bi = (int)(bk & 0xFFFFFFFFull);
    if (lane == 0) knn[(size_t)q * NS + it] = bi;
    if ((bi & 63) == lane) sd[bi] = __uint_as_float(0xFFFFFFFFu);  // max key = invalidated
    __syncthreads();
  }
}

// ---------------- conv1: one thread/row; weights [c][o] in LDS, 4-wide output blocks ----------------
__global__ __launch_bounds__(256) void conv1_kernel(const float* __restrict__ xyz,
                                                    const float* __restrict__ newxyzT,
                                                    const float* __restrict__ points,
                                                    const int* __restrict__ knn,
                                                    const float* __restrict__ w1,
                                                    const float* __restrict__ b1,
                                                    float* __restrict__ z1) {
  __shared__ __align__(16) float wl[67 * 64];   // [c][o]
  __shared__ float bl[64];
  for (int i = threadIdx.x; i < 64 * 67; i += 256) {
    int o = i / 67, c = i % 67;
    wl[c * 64 + o] = w1[i];
  }
  if (threadIdx.x < 64) bl[threadIdx.x] = b1[threadIdx.x];
  __syncthreads();
  int r = blockIdx.x * 256 + threadIdx.x;       // global row (q,s), 0..262143
  int b = r >> 15;
  int q = r >> 5;
  int idx = knn[r];
  float feat[67];
#pragma unroll
  for (int e = 0; e < 3; ++e)
    feat[e] = xyz[((size_t)b * 3 + e) * NN + idx] - newxyzT[(size_t)q * 3 + e];
#pragma unroll
  for (int c = 0; c < 64; ++c)
    feat[3 + c] = points[((size_t)b * 64 + c) * NN + idx];
  for (int og = 0; og < 16; ++og) {
    float a0 = bl[og * 4 + 0], a1 = bl[og * 4 + 1], a2 = bl[og * 4 + 2], a3 = bl[og * 4 + 3];
#pragma unroll
    for (int c = 0; c < 67; ++c) {
      float4 w = *(const float4*)&wl[c * 64 + og * 4];
      a0 = fmaf(feat[c], w.x, a0);
      a1 = fmaf(feat[c], w.y, a1);
      a2 = fmaf(feat[c], w.z, a2);
      a3 = fmaf(feat[c], w.w, a3);
    }
    *((float4*)(z1 + (size_t)r * 64 + og * 4)) = make_float4(a0, a1, a2, a3);
  }
}

// ---------------- per-channel sum/sumsq, f64 accumulation + f64 atomics ----------------
template <int C, typename T>
__global__ __launch_bounds__(256) void stats_kernel(const T* __restrict__ z,
                                                    double* __restrict__ sums, int M) {
  const int RPB = 256 / C;
  int c = threadIdx.x % C;
  int rg = threadIdx.x / C;
  int row = blockIdx.x * RPB + rg;
  int stride = gridDim.x * RPB;
  double s = 0.0, s2 = 0.0;
  for (; row < M; row += stride) {
    double v = (double)ldv(z, (size_t)row * C + c);
    s += v;
    s2 = fma(v, v, s2);
  }
  __shared__ double ls[2][256];
  ls[0][threadIdx.x] = s;
  ls[1][threadIdx.x] = s2;
  __syncthreads();
  if (threadIdx.x < C) {
    for (int k = 1; k < RPB; ++k) {
      s += ls[0][threadIdx.x + k * C];
      s2 += ls[1][threadIdx.x + k * C];
    }
    atomicAdd(&sums[c], s);
    atomicAdd(&sums[C + c], s2);
  }
}

// aff helper: a = g/sqrt(var+eps), cadd = bt - mean*a   (f64 stats -> f32)
__device__ __forceinline__ void bn_aff(const double* st, int C, int c,
                                       const float* g, const float* bt,
                                       float& a, float& cadd) {
  double mean = st[c] / (double)MROWS;
  double var = st[C + c] / (double)MROWS - mean * mean;
  if (var < 0.0) var = 0.0;
  double ad = (double)g[c] / sqrt(var + 1e-5);
  a = (float)ad;
  cadd = (float)((double)bt[c] - mean * ad);
}

// ---------------- conv2: bn1+relu on z1(f32) @ w2^T + b2 -> z2 bf16; [c][o] weights ----------------
__global__ __launch_bounds__(256) void conv2_kernel(const float* __restrict__ z1,
                                                    const double* __restrict__ stats1,
                                                    const float* __restrict__ g1,
                                                    const float* __restrict__ bt1,
                                                    const float* __restrict__ w2,
                                                    const float* __restrict__ b2,
                                                    u16* __restrict__ z2) {
  __shared__ __align__(16) float wl[64 * 64];   // [c][o]
  __shared__ float sa[64], sc[64], bl[64];
  for (int i = threadIdx.x; i < 64 * 64; i += 256) {
    int o = i >> 6, c = i & 63;
    wl[c * 64 + o] = w2[i];
  }
  if (threadIdx.x < 64) {
    bn_aff(stats1, 64, threadIdx.x, g1, bt1, sa[threadIdx.x], sc[threadIdx.x]);
    bl[threadIdx.x] = b2[threadIdx.x];
  }
  __syncthreads();
  int r = blockIdx.x * 256 + threadIdx.x;
  float x[64];
#pragma unroll
  for (int c = 0; c < 64; ++c)
    x[c] = fmaxf(0.f, fmaf(sa[c], z1[(size_t)r * 64 + c], sc[c]));
  for (int og = 0; og < 16; ++og) {
    float a0 = bl[og * 4 + 0], a1 = bl[og * 4 + 1], a2 = bl[og * 4 + 2], a3 = bl[og * 4 + 3];
#pragma unroll
    for (int c = 0; c < 64; ++c) {
      float4 w = *(const float4*)&wl[c * 64 + og * 4];
      a0 = fmaf(x[c], w.x, a0);
      a1 = fmaf(x[c], w.y, a1);
      a2 = fmaf(x[c], w.z, a2);
      a3 = fmaf(x[c], w.w, a3);
    }
    uint2 u;
    u.x = pk2(a0, a1);
    u.y = pk2(a2, a3);
    *((uint2*)(z2 + (size_t)r * 64 + og * 4)) = u;
  }
}

// ---------------- conv3: bn2+relu on z2(bf16) @ w3^T + b3 -> z3 bf16; [c][o] weights ----------------
__global__ __launch_bounds__(256) void conv3_kernel(const u16* __restrict__ z2,
                                                    const double* __restrict__ stats2,
                                                    const float* __restrict__ g2,
                                                    const float* __restrict__ bt2,
                                                    const float* __restrict__ w3,
                                                    const float* __restrict__ b3,
                                                    u16* __restrict__ z3) {
  __shared__ __align__(16) float wl[64 * 128];  // [c][o]
  __shared__ float sa[64], sc[64], bl[128];
  for (int i = threadIdx.x; i < 128 * 64; i += 256) {
    int o = i >> 6, c = i & 63;
    wl[c * 128 + o] = w3[i];
  }
  if (threadIdx.x < 64)
    bn_aff(stats2, 64, threadIdx.x, g2, bt2, sa[threadIdx.x], sc[threadIdx.x]);
  if (threadIdx.x < 128) bl[threadIdx.x] = b3[threadIdx.x];
  __syncthreads();
  int r = blockIdx.x * 256 + threadIdx.x;
  float x[64];
#pragma unroll
  for (int c = 0; c < 64; ++c)
    x[c] = fmaxf(0.f, fmaf(sa[c], bf2f(z2[(size_t)r * 64 + c]), sc[c]));
  for (int og = 0; og < 32; ++og) {
    float a0 = bl[og * 4 + 0], a1 = bl[og * 4 + 1], a2 = bl[og * 4 + 2], a3 = bl[og * 4 + 3];
#pragma unroll
    for (int c = 0; c < 64; ++c) {
      float4 w = *(const float4*)&wl[c * 128 + og * 4];
      a0 = fmaf(x[c], w.x, a0);
      a1 = fmaf(x[c], w.y, a1);
      a2 = fmaf(x[c], w.z, a2);
      a3 = fmaf(x[c], w.w, a3);
    }
    uint2 u;
    u.x = pk2(a0, a1);
    u.y = pk2(a2, a3);
    *((uint2*)(z3 + (size_t)r * 128 + og * 4)) = u;
  }
}

// ---------------- bn3 + max over S (naive): one thread per (o, q) ----------------
__global__ __launch_bounds__(256) void bnmax_naive(const u16* __restrict__ z3,
                                                   const double* __restrict__ stats3,
                                                   const float* __restrict__ g3,
                                                   const float* __restrict__ bt3,
                                                   float* __restrict__ out1) {
  int tid = blockIdx.x * 256 + threadIdx.x;   // 0 .. 128*8192-1
  int o = tid >> 13;                          // 0..127
  int q = tid & 8191;                         // 0..8191
  int b = q >> 10, p = q & 1023;
  float a, cadd;
  bn_aff(stats3, 128, o, g3, bt3, a, cadd);
  float m = -3.4e38f;
  size_t base = (size_t)q * NS * 128 + o;
#pragma unroll
  for (int s = 0; s < NS; ++s) {
    float v = bf2f(z3[base + (size_t)s * 128]);
    m = fmaxf(m, fmaf(a, v, cadd));
  }
  out1[((size_t)b * 128 + o) * NP + p] = m;
}

// ---------------- host launch ----------------
extern "C" void kernel_launch(void* const* d_in, const int* in_sizes, int n_in,
                              void* d_out, int out_size, void* d_ws, size_t ws_size,
                              hipStream_t stream) {
  const float* xyz = (const float*)d_in[0];
  const float* points = (const float*)d_in[1];
  const float* w1 = (const float*)d_in[2];
  const float* b1 = (const float*)d_in[3];
  const float* g1 = (const float*)d_in[4];
  const float* bt1 = (const float*)d_in[5];
  const float* w2 = (const float*)d_in[6];
  const float* b2 = (const float*)d_in[7];
  const float* g2 = (const float*)d_in[8];
  const float* bt2 = (const float*)d_in[9];
  const float* w3 = (const float*)d_in[10];
  const float* b3 = (const float*)d_in[11];
  const float* g3 = (const float*)d_in[12];
  const float* bt3 = (const float*)d_in[13];
  float* out0 = (float*)d_out;             // [8][3][1024]
  float* out1 = out0 + NB * 3 * NP;        // [8][128][1024]

  // Workspace (98 MB):
  //   [0, 96K)        newxyzT f32 [8][1024][3]
  //   [128K, 1.125M)  knn i32 [8][1024][32]
  //   [1.5M, 1.504M)  stats f64 [512]  (L1: 0..127, L2: 128..255, L3: 256..511)
  //   [2M, 66M)       z1 f32 [262144][64]   -> dead after conv2 -> z3 bf16 overlays
  //   [66M, 98M)      z2 bf16 [262144][64]
  char* ws = (char*)d_ws;
  float* newxyzT = (float*)ws;
  int* knn = (int*)(ws + 128 * 1024);
  double* stats = (double*)(ws + 1536 * 1024);
  float* z1 = (float*)(ws + (size_t)2 * 1024 * 1024);
  u16* z3 = (u16*)z1;                                       // alias: z1 dead before conv3
  u16* z2 = (u16*)(ws + (size_t)66 * 1024 * 1024);

  zero_stats<<<2, 256, 0, stream>>>(stats);
  fps_kernel<<<8, 256, 0, stream>>>(xyz, out0, newxyzT);
  knn_expansion_fma<<<NB * NP, 64, 0, stream>>>(xyz, newxyzT, knn);
  conv1_kernel<<<1024, 256, 0, stream>>>(xyz, newxyzT, points, knn, w1, b1, z1);
  stats_kernel<64, float><<<512, 256, 0, stream>>>(z1, stats + 0, MROWS);
  conv2_kernel<<<1024, 256, 0, stream>>>(z1, stats + 0, g1, bt1, w2, b2, z2);
  stats_kernel<64, u16><<<512, 256, 0, stream>>>(z2, stats + 128, MROWS);
  conv3_kernel<<<1024, 256, 0, stream>>>(z2, stats + 128, g2, bt2, w3, b3, z3);
  stats_kernel<128, u16><<<512, 256, 0, stream>>>(z3, stats + 256, MROWS);
  bnmax_naive<<<4096, 256, 0, stream>>>(z3, stats + 256, g3, bt3, out1);
}

// Round 8
// 2344.923 us; speedup vs baseline: 2.1479x; 1.7341x over previous
//
#include <hip/hip_runtime.h>
#include <stdint.h>

typedef unsigned int u32;
typedef unsigned long long u64;
typedef unsigned short u16;

#define NB 8
#define NN 8192
#define NP 1024
#define NS 32
#define MROWS (NB * NP * NS) /* 262144 */

__device__ __forceinline__ u16 f2bf(float f) {
  u32 u = __float_as_uint(f);
  u32 r = u + 0x7FFFu + ((u >> 16) & 1u);   // round-to-nearest-even
  return (u16)(r >> 16);
}
__device__ __forceinline__ float bf2f(u32 h) { return __uint_as_float(h << 16); }
__device__ __forceinline__ u32 pk2(float lo, float hi) {
  return (u32)f2bf(lo) | ((u32)f2bf(hi) << 16);
}
__device__ __forceinline__ float ldv(const float* p, size_t i) { return p[i]; }
__device__ __forceinline__ float ldv(const u16* p, size_t i) { return bf2f(p[i]); }

// ---------------- zero BN stats accumulators (512 doubles) ----------------
__global__ void zero_stats(double* __restrict__ stats) {
  int g = blockIdx.x * 256 + threadIdx.x;
  if (g < 512) stats[g] = 0.0;
}

// ---------------- transpose points [B][64][N] -> [B][N][64] ----------------
__global__ __launch_bounds__(256) void transpose_points(const float* __restrict__ points,
                                                        float* __restrict__ pointsT) {
  __shared__ float t[64][65];
  int b = blockIdx.y, n0 = blockIdx.x * 64;
  int l = threadIdx.x & 63, w = threadIdx.x >> 6;
  const float* pb = points + (size_t)b * 64 * NN;
#pragma unroll
  for (int k = 0; k < 16; ++k) {
    int c = w * 16 + k;
    t[c][l] = pb[(size_t)c * NN + n0 + l];
  }
  __syncthreads();
  float* ob = pointsT + ((size_t)b * NN + n0) * 64;
#pragma unroll
  for (int k = 0; k < 16; ++k) {
    int n = w * 16 + k;
    ob[(size_t)n * 64 + l] = t[l][n];
  }
}

// ---------------- FPS: 256 thr/block, 1 barrier/step, key-only reduce [verified] ----------------
__global__ __launch_bounds__(256) void fps_kernel(const float* __restrict__ xyz,
                                                  float* __restrict__ out0,      // [B][3][P]
                                                  float* __restrict__ newxyzT) { // [B][P][3]
  const int b = blockIdx.x;
  const int t = threadIdx.x;   // 0..255
  const float* xb = xyz + (size_t)b * 3 * NN;
  float px[32], py[32], pz[32], dist[32];
#pragma unroll
  for (int j = 0; j < 32; ++j) {
    int n = t + j * 256;
    px[j] = xb[n];
    py[j] = xb[NN + n];
    pz[j] = xb[2 * NN + n];
    dist[j] = 1e10f;
  }
  __shared__ u64 red[2][4];
  const int lane = t & 63, wid = t >> 6;
  float cx = xb[0], cy = xb[NN], cz = xb[2 * NN];   // farthest = 0 initially
  for (int s = 0; s < NP; ++s) {
    if (t == 0) {   // emit centroid BEFORE update
      out0[b * 3 * NP + s] = cx;
      out0[b * 3 * NP + NP + s] = cy;
      out0[b * 3 * NP + 2 * NP + s] = cz;
      float* qq = newxyzT + ((size_t)b * NP + s) * 3;
      qq[0] = cx; qq[1] = cy; qq[2] = cz;
    }
    u64 bk = 0;
#pragma unroll
    for (int j = 0; j < 32; ++j) {
      float dx = __fsub_rn(px[j], cx), dy = __fsub_rn(py[j], cy), dz = __fsub_rn(pz[j], cz);
      float d = __fadd_rn(__fadd_rn(__fmul_rn(dx, dx), __fmul_rn(dy, dy)), __fmul_rn(dz, dz));
      float dj = fminf(dist[j], d);
      dist[j] = dj;
      u64 key = ((u64)__float_as_uint(dj) << 13) | (u32)(8191 - (t + j * 256));
      bk = key > bk ? key : bk;
    }
#pragma unroll
    for (int m = 32; m > 0; m >>= 1) {
      u64 ok = __shfl_xor(bk, m);
      bk = ok > bk ? ok : bk;
    }
    if (lane == 0) red[s & 1][wid] = bk;
    __syncthreads();   // single barrier: parity buffer protects cross-iter reuse
    u64 r0 = red[s & 1][0], r1 = red[s & 1][1];
    u64 r2 = red[s & 1][2], r3 = red[s & 1][3];
    u64 m01 = r0 > r1 ? r0 : r1;
    u64 m23 = r2 > r3 ? r2 : r3;
    bk = m01 > m23 ? m01 : m23;
    int widx = 8191 - (int)(bk & 8191ull);
    cx = xb[widx]; cy = xb[NN + widx]; cz = xb[2 * NN + widx];  // wave-uniform loads
  }
}

// ---------------- kNN: expansion-FMA keys [FROZEN arithmetic], threshold extract ----------------
// 256 thr/block. Keys (sb<<32)|n are unique -> it-th smallest = min over keys > prev.
// No LDS invalidation writes; one barrier per extraction (parity-buffered cross-wave reduce).
// Output sequence identical to verified extract-with-invalidate kernel.
__global__ __launch_bounds__(256) void knn_kernel(const float* __restrict__ xyz,
                                                  const float* __restrict__ newxyzT,
                                                  int* __restrict__ knn) {
  const int q = blockIdx.x;       // b*1024 + p
  const int b = q >> 10;
  const int t = threadIdx.x;
  __shared__ float sd[NN];        // 32 KB sortable key bits (as float)
  __shared__ u64 red[2][4];
  const float* qp = newxyzT + (size_t)q * 3;
  const float qx = qp[0], qy = qp[1], qz = qp[2];
  const float A = __fadd_rn(__fadd_rn(__fmul_rn(qx, qx), __fmul_rn(qy, qy)), __fmul_rn(qz, qz));
  const float* xb = xyz + (size_t)b * 3 * NN;
#pragma unroll
  for (int j = 0; j < 32; ++j) {
    int n = t + j * 256;
    float x = xb[n], y = xb[NN + n], z = xb[2 * NN + n];
    float dot = fmaf(qz, z, fmaf(qy, y, __fmul_rn(qx, x)));
    float sq = __fadd_rn(__fadd_rn(__fmul_rn(x, x), __fmul_rn(y, y)), __fmul_rn(z, z));
    float d2 = __fadd_rn(__fsub_rn(A, __fmul_rn(2.0f, dot)), sq);
    u32 u = __float_as_uint(d2);
    u32 sb = u ^ (u32)((((int)u) >> 31) | 0x80000000u);  // monotone map (handles negatives)
    sd[n] = __uint_as_float(sb);
  }
  __syncthreads();
  const int lane = t & 63, wid = t >> 6;
  u64 prev = 0;   // keys are (sb<<32)|n with sb>0 for finite d2 -> 0 is below all keys
  for (int it = 0; it < NS; ++it) {
    u64 bk = ~0ull;
#pragma unroll
    for (int j = 0; j < 32; ++j) {
      int n = t + j * 256;
      u64 key = ((u64)__float_as_uint(sd[n]) << 32) | (u32)n;
      if (key > prev && key < bk) bk = key;
    }
#pragma unroll
    for (int m = 32; m > 0; m >>= 1) {
      u64 ok = __shfl_xor(bk, m);
      bk = ok < bk ? ok : bk;
    }
    if (lane == 0) red[it & 1][wid] = bk;
    __syncthreads();
    u64 r0 = red[it & 1][0], r1 = red[it & 1][1];
    u64 r2 = red[it & 1][2], r3 = red[it & 1][3];
    u64 m01 = r0 < r1 ? r0 : r1;
    u64 m23 = r2 < r3 ? r2 : r3;
    bk = m01 < m23 ? m01 : m23;
    if (t == 0) knn[(size_t)q * NS + it] = (int)(bk & 0xFFFFFFFFull);
    prev = bk;
  }
}

// ---------------- conv1: one thread/row; [c][o] weights, pointsT float4 gather ----------------
__global__ __launch_bounds__(256) void conv1_kernel(const float* __restrict__ xyz,
                                                    const float* __restrict__ newxyzT,
                                                    const float* __restrict__ pointsT,
                                                    const int* __restrict__ knn,
                                                    const float* __restrict__ w1,
                                                    const float* __restrict__ b1,
                                                    float* __restrict__ z1) {
  __shared__ __align__(16) float wl[67 * 64];   // [c][o]
  __shared__ float bl[64];
  for (int i = threadIdx.x; i < 64 * 67; i += 256) {
    int o = i / 67, c = i % 67;
    wl[c * 64 + o] = w1[i];
  }
  if (threadIdx.x < 64) bl[threadIdx.x] = b1[threadIdx.x];
  __syncthreads();
  int r = blockIdx.x * 256 + threadIdx.x;       // global row (q,s), 0..262143
  int b = r >> 15;
  int q = r >> 5;
  int idx = knn[r];
  float feat[67];
#pragma unroll
  for (int e = 0; e < 3; ++e)
    feat[e] = xyz[((size_t)b * 3 + e) * NN + idx] - newxyzT[(size_t)q * 3 + e];
  const float4* pa = (const float4*)(pointsT + ((size_t)b * NN + idx) * 64);
#pragma unroll
  for (int cc = 0; cc < 16; ++cc) {
    float4 v = pa[cc];
    feat[3 + cc * 4 + 0] = v.x;
    feat[3 + cc * 4 + 1] = v.y;
    feat[3 + cc * 4 + 2] = v.z;
    feat[3 + cc * 4 + 3] = v.w;
  }
  for (int og = 0; og < 16; ++og) {
    float a0 = bl[og * 4 + 0], a1 = bl[og * 4 + 1], a2 = bl[og * 4 + 2], a3 = bl[og * 4 + 3];
#pragma unroll
    for (int c = 0; c < 67; ++c) {
      float4 w = *(const float4*)&wl[c * 64 + og * 4];
      a0 = fmaf(feat[c], w.x, a0);
      a1 = fmaf(feat[c], w.y, a1);
      a2 = fmaf(feat[c], w.z, a2);
      a3 = fmaf(feat[c], w.w, a3);
    }
    *((float4*)(z1 + (size_t)r * 64 + og * 4)) = make_float4(a0, a1, a2, a3);
  }
}

// ---------------- per-channel sum/sumsq, f64 accumulation + f64 atomics ----------------
template <int C, typename T>
__global__ __launch_bounds__(256) void stats_kernel(const T* __restrict__ z,
                                                    double* __restrict__ sums, int M) {
  const int RPB = 256 / C;
  int c = threadIdx.x % C;
  int rg = threadIdx.x / C;
  int row = blockIdx.x * RPB + rg;
  int stride = gridDim.x * RPB;
  double s = 0.0, s2 = 0.0;
  for (; row < M; row += stride) {
    double v = (double)ldv(z, (size_t)row * C + c);
    s += v;
    s2 = fma(v, v, s2);
  }
  __shared__ double ls[2][256];
  ls[0][threadIdx.x] = s;
  ls[1][threadIdx.x] = s2;
  __syncthreads();
  if (threadIdx.x < C) {
    for (int k = 1; k < RPB; ++k) {
      s += ls[0][threadIdx.x + k * C];
      s2 += ls[1][threadIdx.x + k * C];
    }
    atomicAdd(&sums[c], s);
    atomicAdd(&sums[C + c], s2);
  }
}

// aff helper: a = g/sqrt(var+eps), cadd = bt - mean*a   (f64 stats -> f32)
__device__ __forceinline__ void bn_aff(const double* st, int C, int c,
                                       const float* g, const float* bt,
                                       float& a, float& cadd) {
  double mean = st[c] / (double)MROWS;
  double var = st[C + c] / (double)MROWS - mean * mean;
  if (var < 0.0) var = 0.0;
  double ad = (double)g[c] / sqrt(var + 1e-5);
  a = (float)ad;
  cadd = (float)((double)bt[c] - mean * ad);
}

// ---------------- conv2: bn1+relu on z1(f32) @ w2^T + b2 -> z2 bf16; [c][o] weights ----------------
__global__ __launch_bounds__(256) void conv2_kernel(const float* __restrict__ z1,
                                                    const double* __restrict__ stats1,
                                                    const float* __restrict__ g1,
                                                    const float* __restrict__ bt1,
                                                    const float* __restrict__ w2,
                                                    const float* __restrict__ b2,
                                                    u16* __restrict__ z2) {
  __shared__ __align__(16) float wl[64 * 64];   // [c][o]
  __shared__ float sa[64], sc[64], bl[64];
  for (int i = threadIdx.x; i < 64 * 64; i += 256) {
    int o = i >> 6, c = i & 63;
    wl[c * 64 + o] = w2[i];
  }
  if (threadIdx.x < 64) {
    bn_aff(stats1, 64, threadIdx.x, g1, bt1, sa[threadIdx.x], sc[threadIdx.x]);
    bl[threadIdx.x] = b2[threadIdx.x];
  }
  __syncthreads();
  int r = blockIdx.x * 256 + threadIdx.x;
  float x[64];
#pragma unroll
  for (int c = 0; c < 64; ++c)
    x[c] = fmaxf(0.f, fmaf(sa[c], z1[(size_t)r * 64 + c], sc[c]));
  for (int og = 0; og < 16; ++og) {
    float a0 = bl[og * 4 + 0], a1 = bl[og * 4 + 1], a2 = bl[og * 4 + 2], a3 = bl[og * 4 + 3];
#pragma unroll
    for (int c = 0; c < 64; ++c) {
      float4 w = *(const float4*)&wl[c * 64 + og * 4];
      a0 = fmaf(x[c], w.x, a0);
      a1 = fmaf(x[c], w.y, a1);
      a2 = fmaf(x[c], w.z, a2);
      a3 = fmaf(x[c], w.w, a3);
    }
    uint2 u;
    u.x = pk2(a0, a1);
    u.y = pk2(a2, a3);
    *((uint2*)(z2 + (size_t)r * 64 + og * 4)) = u;
  }
}

// ---------------- conv3: bn2+relu on z2(bf16) @ w3^T + b3 -> z3 bf16; [c][o] weights ----------------
__global__ __launch_bounds__(256) void conv3_kernel(const u16* __restrict__ z2,
                                                    const double* __restrict__ stats2,
                                                    const float* __restrict__ g2,
                                                    const float* __restrict__ bt2,
                                                    const float* __restrict__ w3,
                                                    const float* __restrict__ b3,
                                                    u16* __restrict__ z3) {
  __shared__ __align__(16) float wl[64 * 128];  // [c][o]
  __shared__ float sa[64], sc[64], bl[128];
  for (int i = threadIdx.x; i < 128 * 64; i += 256) {
    int o = i >> 6, c = i & 63;
    wl[c * 128 + o] = w3[i];
  }
  if (threadIdx.x < 64)
    bn_aff(stats2, 64, threadIdx.x, g2, bt2, sa[threadIdx.x], sc[threadIdx.x]);
  if (threadIdx.x < 128) bl[threadIdx.x] = b3[threadIdx.x];
  __syncthreads();
  int r = blockIdx.x * 256 + threadIdx.x;
  float x[64];
#pragma unroll
  for (int c = 0; c < 64; ++c)
    x[c] = fmaxf(0.f, fmaf(sa[c], bf2f(z2[(size_t)r * 64 + c]), sc[c]));
  for (int og = 0; og < 32; ++og) {
    float a0 = bl[og * 4 + 0], a1 = bl[og * 4 + 1], a2 = bl[og * 4 + 2], a3 = bl[og * 4 + 3];
#pragma unroll
    for (int c = 0; c < 64; ++c) {
      float4 w = *(const float4*)&wl[c * 128 + og * 4];
      a0 = fmaf(x[c], w.x, a0);
      a1 = fmaf(x[c], w.y, a1);
      a2 = fmaf(x[c], w.z, a2);
      a3 = fmaf(x[c], w.w, a3);
    }
    uint2 u;
    u.x = pk2(a0, a1);
    u.y = pk2(a2, a3);
    *((uint2*)(z3 + (size_t)r * 128 + og * 4)) = u;
  }
}

// ---------------- bn3 + max over S: coalesced (o = tid&127), aff in LDS ----------------
__global__ __launch_bounds__(256) void bnmax_kernel(const u16* __restrict__ z3,
                                                    const double* __restrict__ stats3,
                                                    const float* __restrict__ g3,
                                                    const float* __restrict__ bt3,
                                                    float* __restrict__ out1) {
  __shared__ float sa[128], sc[128];
  if (threadIdx.x < 128)
    bn_aff(stats3, 128, threadIdx.x, g3, bt3, sa[threadIdx.x], sc[threadIdx.x]);
  __syncthreads();
  int tid = blockIdx.x * 256 + threadIdx.x;   // 0 .. 128*8192-1
  int o = tid & 127;                          // consecutive threads -> consecutive channels
  int q = tid >> 7;                           // 0..8191
  int b = q >> 10, p = q & 1023;
  float a = sa[o], cadd = sc[o];
  float m = -3.4e38f;
  size_t base = (size_t)q * NS * 128 + o;
#pragma unroll
  for (int s = 0; s < NS; ++s) {
    float v = bf2f(z3[base + (size_t)s * 128]);
    m = fmaxf(m, fmaf(a, v, cadd));
  }
  out1[((size_t)b * 128 + o) * NP + p] = m;
}

// ---------------- host launch ----------------
extern "C" void kernel_launch(void* const* d_in, const int* in_sizes, int n_in,
                              void* d_out, int out_size, void* d_ws, size_t ws_size,
                              hipStream_t stream) {
  const float* xyz = (const float*)d_in[0];
  const float* points = (const float*)d_in[1];
  const float* w1 = (const float*)d_in[2];
  const float* b1 = (const float*)d_in[3];
  const float* g1 = (const float*)d_in[4];
  const float* bt1 = (const float*)d_in[5];
  const float* w2 = (const float*)d_in[6];
  const float* b2 = (const float*)d_in[7];
  const float* g2 = (const float*)d_in[8];
  const float* bt2 = (const float*)d_in[9];
  const float* w3 = (const float*)d_in[10];
  const float* b3 = (const float*)d_in[11];
  const float* g3 = (const float*)d_in[12];
  const float* bt3 = (const float*)d_in[13];
  float* out0 = (float*)d_out;             // [8][3][1024]
  float* out1 = out0 + NB * 3 * NP;        // [8][128][1024]

  // Workspace (98 MB):
  //   [0, 96K)        newxyzT f32 [8][1024][3]
  //   [128K, 1.125M)  knn i32 [8][1024][32]
  //   [1.5M, 1.504M)  stats f64 [512]  (L1: 0..127, L2: 128..255, L3: 256..511)
  //   [2M, 66M)       z1 f32 [262144][64]   -> dead after conv2 -> z3 bf16 overlays
  //   [66M, 98M)      z2 bf16 [262144][64]; pointsT f32 (16MB) aliases start, dead pre-conv2
  char* ws = (char*)d_ws;
  float* newxyzT = (float*)ws;
  int* knn = (int*)(ws + 128 * 1024);
  double* stats = (double*)(ws + 1536 * 1024);
  float* z1 = (float*)(ws + (size_t)2 * 1024 * 1024);
  u16* z3 = (u16*)z1;                                       // alias: z1 dead before conv3
  u16* z2 = (u16*)(ws + (size_t)66 * 1024 * 1024);
  float* pointsT = (float*)z2;                              // alias: dead before conv2 writes z2

  zero_stats<<<2, 256, 0, stream>>>(stats);
  transpose_points<<<dim3(128, 8), 256, 0, stream>>>(points, pointsT);
  fps_kernel<<<8, 256, 0, stream>>>(xyz, out0, newxyzT);
  knn_kernel<<<NB * NP, 256, 0, stream>>>(xyz, newxyzT, knn);
  conv1_kernel<<<1024, 256, 0, stream>>>(xyz, newxyzT, pointsT, knn, w1, b1, z1);
  stats_kernel<64, float><<<512, 256, 0, stream>>>(z1, stats + 0, MROWS);
  conv2_kernel<<<1024, 256, 0, stream>>>(z1, stats + 0, g1, bt1, w2, b2, z2);
  stats_kernel<64, u16><<<512, 256, 0, stream>>>(z2, stats + 128, MROWS);
  conv3_kernel<<<1024, 256, 0, stream>>>(z2, stats + 128, g2, bt2, w3, b3, z3);
  stats_kernel<128, u16><<<512, 256, 0, stream>>>(z3, stats + 256, MROWS);
  bnmax_kernel<<<4096, 256, 0, stream>>>(z3, stats + 256, g3, bt3, out1);
}